// Round 1
// baseline (1112.512 us; speedup 1.0000x reference)
//
#include <hip/hip_runtime.h>

#define DIN 512
#define DHID 128
#define DOUT 4
#define SCAN_B 256

// ---------- edge dtype normalization ----------
// Reference declares edge_index as int64; harness doc says int32. Detect on
// device: if the data is little-endian int64 with values < 2^31, every odd
// int32 word is 0. For genuine int32 random indices in [0,1e5), P(8 specific
// words all zero) ~ 1e-40. Data-dependent but input is identical every call.
__global__ void detect_i64_k(const int* __restrict__ raw, int* __restrict__ flag) {
  if (blockIdx.x == 0 && threadIdx.x == 0) {
    int z = 1;
    for (int k = 0; k < 8; ++k)
      if (raw[2 * k + 1] != 0) z = 0;
    flag[0] = z;
  }
}

__global__ __launch_bounds__(256) void convert_k(const int* __restrict__ raw,
                                                 const int* __restrict__ flag,
                                                 int* __restrict__ src,
                                                 int* __restrict__ dst, int E) {
  int e = blockIdx.x * 256 + threadIdx.x;
  if (e >= E) return;
  if (flag[0]) {  // int64 layout: element k lives at int32 index 2k (low word)
    src[e] = raw[2 * (size_t)e];
    dst[e] = raw[2 * ((size_t)E + e)];
  } else {
    src[e] = raw[e];
    dst[e] = raw[(size_t)E + e];
  }
}

__global__ void zero_k(int* __restrict__ p, int n) {
  int i = blockIdx.x * 256 + threadIdx.x;
  if (i < n) p[i] = 0;
}

__global__ __launch_bounds__(256) void count_k(const int* __restrict__ dst,
                                               int* __restrict__ cnt, int E) {
  int e = blockIdx.x * 256 + threadIdx.x;
  if (e < E) atomicAdd(&cnt[dst[e]], 1);
}

__global__ void dis_k(const int* __restrict__ cnt, float* __restrict__ dis, int N) {
  int i = blockIdx.x * 256 + threadIdx.x;
  if (i < N) dis[i] = rsqrtf((float)cnt[i] + 1.0f);  // deg = in-degree + self-loop
}

// ---------- exclusive scan (3 kernels; N=100K -> 391 block sums <= 512) ----------
__global__ __launch_bounds__(SCAN_B) void scan1_k(const int* __restrict__ cnt,
                                                  int* __restrict__ offs,
                                                  int* __restrict__ bsum, int N) {
  __shared__ int sm[SCAN_B];
  int t = threadIdx.x;
  int i = blockIdx.x * SCAN_B + t;
  int v = (i < N) ? cnt[i] : 0;
  int x = v;
  sm[t] = x;
  __syncthreads();
  #pragma unroll
  for (int o = 1; o < SCAN_B; o <<= 1) {
    int y = (t >= o) ? sm[t - o] : 0;
    __syncthreads();
    x += y;
    sm[t] = x;
    __syncthreads();
  }
  if (i < N) offs[i] = x - v;              // within-block exclusive
  if (t == SCAN_B - 1) bsum[blockIdx.x] = x;
}

__global__ __launch_bounds__(512) void scan2_k(int* __restrict__ bsum, int nb) {
  __shared__ int sm[512];
  int t = threadIdx.x;
  int v = (t < nb) ? bsum[t] : 0;
  int x = v;
  sm[t] = x;
  __syncthreads();
  #pragma unroll
  for (int o = 1; o < 512; o <<= 1) {
    int y = (t >= o) ? sm[t - o] : 0;
    __syncthreads();
    x += y;
    sm[t] = x;
    __syncthreads();
  }
  if (t < nb) bsum[t] = x - v;             // exclusive block offsets
}

__global__ void scan3_k(int* __restrict__ offs, const int* __restrict__ bsum,
                        int* __restrict__ cur, int N, int E) {
  int i = blockIdx.x * 256 + threadIdx.x;
  if (i < N) {
    int o = offs[i] + bsum[i / SCAN_B];
    offs[i] = o;
    cur[i] = o;
  }
  if (i == 0) offs[N] = E;
}

__global__ __launch_bounds__(256) void fill_k(const int* __restrict__ src,
                                              const int* __restrict__ dst,
                                              int* __restrict__ cur,
                                              int* __restrict__ csr, int E) {
  int e = blockIdx.x * 256 + threadIdx.x;
  if (e >= E) return;
  int d = dst[e];
  int p = atomicAdd(&cur[d], 1);
  csr[p] = src[e];
}

// ---------- GEMM1: h = X @ W1, fp32 vector-ALU, 64x128 tile ----------
__global__ __launch_bounds__(256) void gemm1_k(const float* __restrict__ A,
                                               const float* __restrict__ B,
                                               float* __restrict__ C, int N) {
  __shared__ float As[64][33];   // +1 pad: inner reads As[r][kk], banks differ by r
  __shared__ float Bs[32][128];
  const int tid = threadIdx.x;
  const int tx = tid & 15;       // 16 col-groups
  const int ty = tid >> 4;       // 16 row-groups x 4 rows
  const int m0 = blockIdx.x * 64;
  float acc[4][8];
  #pragma unroll
  for (int i = 0; i < 4; ++i)
    #pragma unroll
    for (int j = 0; j < 8; ++j) acc[i][j] = 0.f;

  for (int k0 = 0; k0 < DIN; k0 += 32) {
    #pragma unroll
    for (int l = 0; l < 2; ++l) {          // A tile: 64x32 = 512 float4
      int idx = tid + l * 256;
      int r = idx >> 3, c = (idx & 7) * 4;
      int gr = m0 + r;
      float4 v = make_float4(0.f, 0.f, 0.f, 0.f);
      if (gr < N) v = *(const float4*)(A + (size_t)gr * DIN + k0 + c);
      As[r][c + 0] = v.x; As[r][c + 1] = v.y; As[r][c + 2] = v.z; As[r][c + 3] = v.w;
    }
    #pragma unroll
    for (int l = 0; l < 4; ++l) {          // B tile: 32x128 = 1024 float4
      int idx = tid + l * 256;
      int r = idx >> 5, c = (idx & 31) * 4;
      *(float4*)(&Bs[r][c]) = *(const float4*)(B + (size_t)(k0 + r) * DHID + c);
    }
    __syncthreads();
    #pragma unroll
    for (int kk = 0; kk < 32; ++kk) {
      float av[4];
      #pragma unroll
      for (int i = 0; i < 4; ++i) av[i] = As[ty * 4 + i][kk];
      float4 b0 = *(const float4*)(&Bs[kk][tx * 4]);
      float4 b1 = *(const float4*)(&Bs[kk][64 + tx * 4]);
      #pragma unroll
      for (int i = 0; i < 4; ++i) {
        acc[i][0] = fmaf(av[i], b0.x, acc[i][0]);
        acc[i][1] = fmaf(av[i], b0.y, acc[i][1]);
        acc[i][2] = fmaf(av[i], b0.z, acc[i][2]);
        acc[i][3] = fmaf(av[i], b0.w, acc[i][3]);
        acc[i][4] = fmaf(av[i], b1.x, acc[i][4]);
        acc[i][5] = fmaf(av[i], b1.y, acc[i][5]);
        acc[i][6] = fmaf(av[i], b1.z, acc[i][6]);
        acc[i][7] = fmaf(av[i], b1.w, acc[i][7]);
      }
    }
    __syncthreads();
  }
  #pragma unroll
  for (int i = 0; i < 4; ++i) {
    int r = m0 + ty * 4 + i;
    if (r < N) {
      *(float4*)(C + (size_t)r * DHID + tx * 4) =
          make_float4(acc[i][0], acc[i][1], acc[i][2], acc[i][3]);
      *(float4*)(C + (size_t)r * DHID + 64 + tx * 4) =
          make_float4(acc[i][4], acc[i][5], acc[i][6], acc[i][7]);
    }
  }
}

// ---------- fused: agg1 (CSR, no atomics) + bias + relu + @W2 -> g[N][4] ----------
// One wave per dst node. Lane owns features f=2*lane, 2*lane+1.
// agg = dis[i] * sum_e h[src_e]*dis[src_e]  (+ self h[i]*dis[i]^2), then relu(+b1),
// then project to 4 dims via per-lane partials + shfl_xor butterfly.
__global__ __launch_bounds__(256) void agg1_k(const float* __restrict__ h,
                                              const float* __restrict__ dis,
                                              const int* __restrict__ offs,
                                              const int* __restrict__ csr,
                                              const float* __restrict__ W2,
                                              const float* __restrict__ b1,
                                              float* __restrict__ g, int N) {
  const int wid = threadIdx.x >> 6;
  const int lane = threadIdx.x & 63;
  const int i = blockIdx.x * 4 + wid;
  if (i >= N) return;
  const int f = lane * 2;
  float ax = 0.f, ay = 0.f;
  const int beg = offs[i], end = offs[i + 1];
  for (int base = beg; base < end; base += 64) {
    int sj = 0;
    float wj = 0.f;
    if (base + lane < end) {        // coalesced cooperative load of up to 64 edges
      sj = csr[base + lane];
      wj = dis[sj];
    }
    const int n = min(64, end - base);
    for (int t = 0; t < n; ++t) {   // broadcast edge by shuffle; gathers independent
      int s = __shfl(sj, t, 64);
      float w = __shfl(wj, t, 64);
      float2 hv = *(const float2*)(h + (size_t)s * DHID + f);
      ax = fmaf(hv.x, w, ax);
      ay = fmaf(hv.y, w, ay);
    }
  }
  const float di = dis[i];
  const float d2 = di * di;
  float2 hi = *(const float2*)(h + (size_t)i * DHID + f);
  float v0 = fmaxf(fmaf(ax, di, hi.x * d2) + b1[f], 0.f);
  float v1 = fmaxf(fmaf(ay, di, hi.y * d2) + b1[f + 1], 0.f);
  // project: g[i][c] = sum_k h1[k] * W2[k][c]
  float p0 = fmaf(v0, W2[f * 4 + 0], v1 * W2[f * 4 + 4]);
  float p1 = fmaf(v0, W2[f * 4 + 1], v1 * W2[f * 4 + 5]);
  float p2 = fmaf(v0, W2[f * 4 + 2], v1 * W2[f * 4 + 6]);
  float p3 = fmaf(v0, W2[f * 4 + 3], v1 * W2[f * 4 + 7]);
  #pragma unroll
  for (int o = 32; o > 0; o >>= 1) {
    p0 += __shfl_xor(p0, o, 64);
    p1 += __shfl_xor(p1, o, 64);
    p2 += __shfl_xor(p2, o, 64);
    p3 += __shfl_xor(p3, o, 64);
  }
  if (lane == 0) *(float4*)(g + (size_t)i * DOUT) = make_float4(p0, p1, p2, p3);
}

// ---------- layer-2 aggregation: out = dis[i]*sum g[s]*dis[s] + g[i]*dis^2 + b2 ----
__global__ __launch_bounds__(256) void agg2_k(const float* __restrict__ g,
                                              const float* __restrict__ dis,
                                              const int* __restrict__ offs,
                                              const int* __restrict__ csr,
                                              const float* __restrict__ b2,
                                              float* __restrict__ out, int N) {
  int i = blockIdx.x * 256 + threadIdx.x;
  if (i >= N) return;
  float a0 = 0.f, a1 = 0.f, a2 = 0.f, a3 = 0.f;
  const int beg = offs[i], end = offs[i + 1];
  for (int j = beg; j < end; ++j) {
    int s = csr[j];
    float w = dis[s];
    float4 gv = *(const float4*)(g + (size_t)s * DOUT);
    a0 = fmaf(gv.x, w, a0);
    a1 = fmaf(gv.y, w, a1);
    a2 = fmaf(gv.z, w, a2);
    a3 = fmaf(gv.w, w, a3);
  }
  const float di = dis[i];
  const float d2 = di * di;
  float4 gi = *(const float4*)(g + (size_t)i * DOUT);
  float4 o4;
  o4.x = fmaf(a0, di, gi.x * d2) + b2[0];
  o4.y = fmaf(a1, di, gi.y * d2) + b2[1];
  o4.z = fmaf(a2, di, gi.z * d2) + b2[2];
  o4.w = fmaf(a3, di, gi.w * d2) + b2[3];
  *(float4*)(out + (size_t)i * DOUT) = o4;
}

extern "C" void kernel_launch(void* const* d_in, const int* in_sizes, int n_in,
                              void* d_out, int out_size, void* d_ws, size_t ws_size,
                              hipStream_t stream) {
  const float* x  = (const float*)d_in[0];
  const int*   raw = (const int*)d_in[1];
  const float* W1 = (const float*)d_in[2];
  const float* b1 = (const float*)d_in[3];
  const float* W2 = (const float*)d_in[4];
  const float* b2 = (const float*)d_in[5];
  float* out = (float*)d_out;

  const int N = in_sizes[0] / DIN;   // 100000
  const int E = in_sizes[1] / 2;     // 3200000 (element count is dtype-agnostic)

  // carve workspace (~91 MB), 256B-aligned
  char* ws = (char*)d_ws;
  size_t off = 0;
  auto carve = [&](size_t bytes) -> char* {
    char* p = ws + off;
    off = (off + bytes + 255) & ~(size_t)255;
    return p;
  };
  int*   src  = (int*)carve((size_t)E * 4);
  int*   dst  = (int*)carve((size_t)E * 4);
  int*   cnt  = (int*)carve((size_t)N * 4);
  float* dis  = (float*)carve((size_t)N * 4);
  int*   offs = (int*)carve((size_t)(N + 1) * 4);
  int*   cur  = (int*)carve((size_t)N * 4);
  int*   csr  = (int*)carve((size_t)E * 4);
  int*   bsum = (int*)carve(512 * 4);
  int*   flag = (int*)carve(256);
  float* h    = (float*)carve((size_t)N * DHID * 4);
  float* g    = (float*)carve((size_t)N * DOUT * 4);
  (void)ws_size; (void)n_in; (void)out_size;

  const int gE = (E + 255) / 256;
  const int gN = (N + 255) / 256;
  const int nb = (N + SCAN_B - 1) / SCAN_B;   // 391 <= 512

  detect_i64_k<<<1, 64, 0, stream>>>(raw, flag);
  convert_k<<<gE, 256, 0, stream>>>(raw, flag, src, dst, E);
  zero_k<<<gN, 256, 0, stream>>>(cnt, N);
  count_k<<<gE, 256, 0, stream>>>(dst, cnt, E);
  dis_k<<<gN, 256, 0, stream>>>(cnt, dis, N);
  scan1_k<<<nb, SCAN_B, 0, stream>>>(cnt, offs, bsum, N);
  scan2_k<<<1, 512, 0, stream>>>(bsum, nb);
  scan3_k<<<gN, 256, 0, stream>>>(offs, bsum, cur, N, E);
  fill_k<<<gE, 256, 0, stream>>>(src, dst, cur, csr, E);
  gemm1_k<<<(N + 63) / 64, 256, 0, stream>>>(x, W1, h, N);
  agg1_k<<<(N + 3) / 4, 256, 0, stream>>>(h, dis, offs, csr, W2, b1, g, N);
  agg2_k<<<gN, 256, 0, stream>>>(g, dis, offs, csr, b2, out, N);
}

// Round 2
// 893.075 us; speedup vs baseline: 1.2457x; 1.2457x over previous
//
#include <hip/hip_runtime.h>

#define DIN 512
#define DHID 128
#define DOUT 4
#define SCAN_B 256
#define BSH 8                 // bucket = 256 nodes
#define PA_CHUNK 8192         // edges staged per binA block (32/thread)

// ---------- edge dtype detection (int64 vs int32 ABI) ----------
__global__ void detect_i64_k(const int* __restrict__ raw, int* __restrict__ flag) {
  if (blockIdx.x == 0 && threadIdx.x == 0) {
    int z = 1;
    for (int k = 0; k < 8; ++k)
      if (raw[2 * k + 1] != 0) z = 0;
    flag[0] = z;
  }
}

__global__ void zero_k(int* __restrict__ p, int n) {
  int i = blockIdx.x * 256 + threadIdx.x;
  if (i < n) p[i] = 0;
}

// degree count straight from raw edge buffer (dst half)
__global__ __launch_bounds__(256) void count_k(const int* __restrict__ raw,
                                               const int* __restrict__ flag,
                                               int* __restrict__ cnt, int E) {
  int e = blockIdx.x * 256 + threadIdx.x;
  if (e >= E) return;
  int d = flag[0] ? raw[2 * ((size_t)E + e)] : raw[(size_t)E + e];
  atomicAdd(&cnt[d], 1);
}

__global__ void dis_k(const int* __restrict__ cnt, float* __restrict__ dis, int N) {
  int i = blockIdx.x * 256 + threadIdx.x;
  if (i < N) dis[i] = rsqrtf((float)cnt[i] + 1.0f);  // deg = in-degree + self-loop
}

// ---------- exclusive scan over cnt -> offs (3 kernels) ----------
__global__ __launch_bounds__(SCAN_B) void scan1_k(const int* __restrict__ cnt,
                                                  int* __restrict__ offs,
                                                  int* __restrict__ bsum, int N) {
  __shared__ int sm[SCAN_B];
  int t = threadIdx.x;
  int i = blockIdx.x * SCAN_B + t;
  int v = (i < N) ? cnt[i] : 0;
  int x = v;
  sm[t] = x;
  __syncthreads();
  #pragma unroll
  for (int o = 1; o < SCAN_B; o <<= 1) {
    int y = (t >= o) ? sm[t - o] : 0;
    __syncthreads();
    x += y;
    sm[t] = x;
    __syncthreads();
  }
  if (i < N) offs[i] = x - v;
  if (t == SCAN_B - 1) bsum[blockIdx.x] = x;
}

__global__ __launch_bounds__(512) void scan2_k(int* __restrict__ bsum, int nb) {
  __shared__ int sm[512];
  int t = threadIdx.x;
  int v = (t < nb) ? bsum[t] : 0;
  int x = v;
  sm[t] = x;
  __syncthreads();
  #pragma unroll
  for (int o = 1; o < 512; o <<= 1) {
    int y = (t >= o) ? sm[t - o] : 0;
    __syncthreads();
    x += y;
    sm[t] = x;
    __syncthreads();
  }
  if (t < nb) bsum[t] = x - v;
}

__global__ void scan3_k(int* __restrict__ offs, const int* __restrict__ bsum,
                        int N, int E) {
  int i = blockIdx.x * 256 + threadIdx.x;
  if (i < N) offs[i] = offs[i] + bsum[i / SCAN_B];
  if (i == 0) offs[N] = E;
}

// bucket cursors = offs at bucket starts
__global__ void bcur_k(const int* __restrict__ offs, int* __restrict__ bcur,
                       int nbkt, int N) {
  int b = blockIdx.x * 256 + threadIdx.x;
  if (b < nbkt) bcur[b] = offs[min(b << BSH, N)];
}

// ---------- binA: scatter (src,dst) pairs into dst-bucketed order ----------
// LDS histogram -> one global atomic per (block,bucket) reserving a contiguous
// run -> contiguous pair writes. Kills fill_k's 16x write amplification.
__global__ __launch_bounds__(256) void binA_k(const int* __restrict__ raw,
                                              const int* __restrict__ flag,
                                              int* __restrict__ bcur,
                                              uint2* __restrict__ pairs, int E) {
  __shared__ int hist[512];
  __shared__ int base[512];
  const int tid = threadIdx.x;
  const int f = flag[0];
  const size_t e0 = (size_t)blockIdx.x * PA_CHUNK;
  for (int i = tid; i < 512; i += 256) hist[i] = 0;
  __syncthreads();
  int es[32], ed[32];
  #pragma unroll
  for (int k = 0; k < 32; ++k) {
    size_t e = e0 + (size_t)k * 256 + tid;
    if (e < (size_t)E) {
      es[k] = f ? raw[2 * e] : raw[e];
      ed[k] = f ? raw[2 * ((size_t)E + e)] : raw[(size_t)E + e];
      atomicAdd(&hist[ed[k] >> BSH], 1);
    } else {
      ed[k] = -1;
    }
  }
  __syncthreads();
  for (int i = tid; i < 512; i += 256) {
    int c = hist[i];
    base[i] = c ? atomicAdd(&bcur[i], c) : 0;  // only this thread touches hist[i]
    hist[i] = 0;                               // reuse as local cursor
  }
  __syncthreads();
  #pragma unroll
  for (int k = 0; k < 32; ++k) {
    if (ed[k] >= 0) {
      int b = ed[k] >> BSH;
      int pos = base[b] + atomicAdd(&hist[b], 1);
      pairs[pos] = make_uint2((unsigned)es[k], (unsigned)ed[k]);
    }
  }
}

// ---------- binB: per-bucket CSR fill, LDS counters, span-local writes ----------
__global__ __launch_bounds__(256) void binB_k(const uint2* __restrict__ pairs,
                                              const int* __restrict__ offs,
                                              int* __restrict__ csr, int N) {
  __shared__ int lcnt[256];
  const int tid = threadIdx.x;
  const int n0 = blockIdx.x << BSH;
  const int lo = offs[n0];
  const int hi = offs[min(n0 + 256, N)];
  lcnt[tid] = 0;
  __syncthreads();
  for (int j = lo + tid; j < hi; j += 256) {
    uint2 p = pairs[j];
    int pos = offs[p.y] + atomicAdd(&lcnt[(int)p.y - n0], 1);
    csr[pos] = (int)p.x;   // write lands in this bucket's ~32KB span -> L2 absorbs
  }
}

// ---------- GEMM1: h = X @ W1, fp32 vector-ALU, 64x128 tile ----------
__global__ __launch_bounds__(256) void gemm1_k(const float* __restrict__ A,
                                               const float* __restrict__ B,
                                               float* __restrict__ C, int N) {
  __shared__ float As[64][33];
  __shared__ float Bs[32][128];
  const int tid = threadIdx.x;
  const int tx = tid & 15;
  const int ty = tid >> 4;
  const int m0 = blockIdx.x * 64;
  float acc[4][8];
  #pragma unroll
  for (int i = 0; i < 4; ++i)
    #pragma unroll
    for (int j = 0; j < 8; ++j) acc[i][j] = 0.f;

  for (int k0 = 0; k0 < DIN; k0 += 32) {
    #pragma unroll
    for (int l = 0; l < 2; ++l) {
      int idx = tid + l * 256;
      int r = idx >> 3, c = (idx & 7) * 4;
      int gr = m0 + r;
      float4 v = make_float4(0.f, 0.f, 0.f, 0.f);
      if (gr < N) v = *(const float4*)(A + (size_t)gr * DIN + k0 + c);
      As[r][c + 0] = v.x; As[r][c + 1] = v.y; As[r][c + 2] = v.z; As[r][c + 3] = v.w;
    }
    #pragma unroll
    for (int l = 0; l < 4; ++l) {
      int idx = tid + l * 256;
      int r = idx >> 5, c = (idx & 31) * 4;
      *(float4*)(&Bs[r][c]) = *(const float4*)(B + (size_t)(k0 + r) * DHID + c);
    }
    __syncthreads();
    #pragma unroll
    for (int kk = 0; kk < 32; ++kk) {
      float av[4];
      #pragma unroll
      for (int i = 0; i < 4; ++i) av[i] = As[ty * 4 + i][kk];
      float4 b0 = *(const float4*)(&Bs[kk][tx * 4]);
      float4 b1 = *(const float4*)(&Bs[kk][64 + tx * 4]);
      #pragma unroll
      for (int i = 0; i < 4; ++i) {
        acc[i][0] = fmaf(av[i], b0.x, acc[i][0]);
        acc[i][1] = fmaf(av[i], b0.y, acc[i][1]);
        acc[i][2] = fmaf(av[i], b0.z, acc[i][2]);
        acc[i][3] = fmaf(av[i], b0.w, acc[i][3]);
        acc[i][4] = fmaf(av[i], b1.x, acc[i][4]);
        acc[i][5] = fmaf(av[i], b1.y, acc[i][5]);
        acc[i][6] = fmaf(av[i], b1.z, acc[i][6]);
        acc[i][7] = fmaf(av[i], b1.w, acc[i][7]);
      }
    }
    __syncthreads();
  }
  #pragma unroll
  for (int i = 0; i < 4; ++i) {
    int r = m0 + ty * 4 + i;
    if (r < N) {
      *(float4*)(C + (size_t)r * DHID + tx * 4) =
          make_float4(acc[i][0], acc[i][1], acc[i][2], acc[i][3]);
      *(float4*)(C + (size_t)r * DHID + 64 + tx * 4) =
          make_float4(acc[i][4], acc[i][5], acc[i][6], acc[i][7]);
    }
  }
}

// ---------- fused: agg1 (CSR) + bias + relu + @W2 -> g[N][4] ----------
__global__ __launch_bounds__(256) void agg1_k(const float* __restrict__ h,
                                              const float* __restrict__ dis,
                                              const int* __restrict__ offs,
                                              const int* __restrict__ csr,
                                              const float* __restrict__ W2,
                                              const float* __restrict__ b1,
                                              float* __restrict__ g, int N) {
  const int wid = threadIdx.x >> 6;
  const int lane = threadIdx.x & 63;
  const int i = blockIdx.x * 4 + wid;
  if (i >= N) return;
  const int f = lane * 2;
  float ax = 0.f, ay = 0.f;
  const int beg = offs[i], end = offs[i + 1];
  for (int base = beg; base < end; base += 64) {
    int sj = 0;
    float wj = 0.f;
    if (base + lane < end) {
      sj = csr[base + lane];
      wj = dis[sj];
    }
    const int n = min(64, end - base);
    for (int t = 0; t < n; ++t) {
      int s = __shfl(sj, t, 64);
      float w = __shfl(wj, t, 64);
      float2 hv = *(const float2*)(h + (size_t)s * DHID + f);
      ax = fmaf(hv.x, w, ax);
      ay = fmaf(hv.y, w, ay);
    }
  }
  const float di = dis[i];
  const float d2 = di * di;
  float2 hi = *(const float2*)(h + (size_t)i * DHID + f);
  float v0 = fmaxf(fmaf(ax, di, hi.x * d2) + b1[f], 0.f);
  float v1 = fmaxf(fmaf(ay, di, hi.y * d2) + b1[f + 1], 0.f);
  float p0 = fmaf(v0, W2[f * 4 + 0], v1 * W2[f * 4 + 4]);
  float p1 = fmaf(v0, W2[f * 4 + 1], v1 * W2[f * 4 + 5]);
  float p2 = fmaf(v0, W2[f * 4 + 2], v1 * W2[f * 4 + 6]);
  float p3 = fmaf(v0, W2[f * 4 + 3], v1 * W2[f * 4 + 7]);
  #pragma unroll
  for (int o = 32; o > 0; o >>= 1) {
    p0 += __shfl_xor(p0, o, 64);
    p1 += __shfl_xor(p1, o, 64);
    p2 += __shfl_xor(p2, o, 64);
    p3 += __shfl_xor(p3, o, 64);
  }
  if (lane == 0) *(float4*)(g + (size_t)i * DOUT) = make_float4(p0, p1, p2, p3);
}

// ---------- layer-2 aggregation ----------
__global__ __launch_bounds__(256) void agg2_k(const float* __restrict__ g,
                                              const float* __restrict__ dis,
                                              const int* __restrict__ offs,
                                              const int* __restrict__ csr,
                                              const float* __restrict__ b2,
                                              float* __restrict__ out, int N) {
  int i = blockIdx.x * 256 + threadIdx.x;
  if (i >= N) return;
  float a0 = 0.f, a1 = 0.f, a2 = 0.f, a3 = 0.f;
  const int beg = offs[i], end = offs[i + 1];
  for (int j = beg; j < end; ++j) {
    int s = csr[j];
    float w = dis[s];
    float4 gv = *(const float4*)(g + (size_t)s * DOUT);
    a0 = fmaf(gv.x, w, a0);
    a1 = fmaf(gv.y, w, a1);
    a2 = fmaf(gv.z, w, a2);
    a3 = fmaf(gv.w, w, a3);
  }
  const float di = dis[i];
  const float d2 = di * di;
  float4 gi = *(const float4*)(g + (size_t)i * DOUT);
  float4 o4;
  o4.x = fmaf(a0, di, gi.x * d2) + b2[0];
  o4.y = fmaf(a1, di, gi.y * d2) + b2[1];
  o4.z = fmaf(a2, di, gi.z * d2) + b2[2];
  o4.w = fmaf(a3, di, gi.w * d2) + b2[3];
  *(float4*)(out + (size_t)i * DOUT) = o4;
}

extern "C" void kernel_launch(void* const* d_in, const int* in_sizes, int n_in,
                              void* d_out, int out_size, void* d_ws, size_t ws_size,
                              hipStream_t stream) {
  const float* x  = (const float*)d_in[0];
  const int*   raw = (const int*)d_in[1];
  const float* W1 = (const float*)d_in[2];
  const float* b1 = (const float*)d_in[3];
  const float* W2 = (const float*)d_in[4];
  const float* b2 = (const float*)d_in[5];
  float* out = (float*)d_out;

  const int N = in_sizes[0] / DIN;   // 100000
  const int E = in_sizes[1] / 2;     // 3200000

  char* ws = (char*)d_ws;
  size_t off = 0;
  auto carve = [&](size_t bytes) -> char* {
    char* p = ws + off;
    off = (off + bytes + 255) & ~(size_t)255;
    return p;
  };
  int*   cnt  = (int*)carve((size_t)N * 4);
  float* dis  = (float*)carve((size_t)N * 4);
  int*   offs = (int*)carve((size_t)(N + 1) * 4);
  int*   csr  = (int*)carve((size_t)E * 4);
  uint2* pairs= (uint2*)carve((size_t)E * 8);
  int*   bsum = (int*)carve(512 * 4);
  int*   bcur = (int*)carve(512 * 4);
  int*   flag = (int*)carve(256);
  float* h    = (float*)carve((size_t)N * DHID * 4);
  float* g    = (float*)carve((size_t)N * DOUT * 4);
  (void)ws_size; (void)n_in; (void)out_size;

  const int gE = (E + 255) / 256;
  const int gN = (N + 255) / 256;
  const int nb = (N + SCAN_B - 1) / SCAN_B;       // 391 <= 512
  const int nbkt = (N + (1 << BSH) - 1) >> BSH;   // 391
  const int gA = (E + PA_CHUNK - 1) / PA_CHUNK;   // 391

  detect_i64_k<<<1, 64, 0, stream>>>(raw, flag);
  zero_k<<<gN, 256, 0, stream>>>(cnt, N);
  count_k<<<gE, 256, 0, stream>>>(raw, flag, cnt, E);
  dis_k<<<gN, 256, 0, stream>>>(cnt, dis, N);
  scan1_k<<<nb, SCAN_B, 0, stream>>>(cnt, offs, bsum, N);
  scan2_k<<<1, 512, 0, stream>>>(bsum, nb);
  scan3_k<<<gN, 256, 0, stream>>>(offs, bsum, N, E);
  bcur_k<<<2, 256, 0, stream>>>(offs, bcur, nbkt, N);
  binA_k<<<gA, 256, 0, stream>>>(raw, flag, bcur, pairs, E);
  binB_k<<<nbkt, 256, 0, stream>>>(pairs, offs, csr, N);
  gemm1_k<<<(N + 63) / 64, 256, 0, stream>>>(x, W1, h, N);
  agg1_k<<<(N + 3) / 4, 256, 0, stream>>>(h, dis, offs, csr, W2, b1, g, N);
  agg2_k<<<gN, 256, 0, stream>>>(g, dis, offs, csr, b2, out, N);
}

// Round 3
// 833.009 us; speedup vs baseline: 1.3355x; 1.0721x over previous
//
#include <hip/hip_runtime.h>
#include <hip/hip_fp16.h>

#define DIN 512
#define DHID 128
#define DOUT 4
#define SCAN_B 256
#define BSH 8                 // bucket = 256 nodes
#define PA_CHUNK 8192         // edges staged per binA block (32/thread)

// ---------- edge dtype detection (int64 vs int32 ABI) ----------
__global__ void detect_i64_k(const int* __restrict__ raw, int* __restrict__ flag) {
  if (blockIdx.x == 0 && threadIdx.x == 0) {
    int z = 1;
    for (int k = 0; k < 8; ++k)
      if (raw[2 * k + 1] != 0) z = 0;
    flag[0] = z;
  }
}

__global__ void zero_k(int* __restrict__ p, int n) {
  int i = blockIdx.x * 256 + threadIdx.x;
  if (i < n) p[i] = 0;
}

__global__ __launch_bounds__(256) void count_k(const int* __restrict__ raw,
                                               const int* __restrict__ flag,
                                               int* __restrict__ cnt, int E) {
  int e = blockIdx.x * 256 + threadIdx.x;
  if (e >= E) return;
  int d = flag[0] ? raw[2 * ((size_t)E + e)] : raw[(size_t)E + e];
  atomicAdd(&cnt[d], 1);
}

__global__ void dis_k(const int* __restrict__ cnt, float* __restrict__ dis, int N) {
  int i = blockIdx.x * 256 + threadIdx.x;
  if (i < N) dis[i] = rsqrtf((float)cnt[i] + 1.0f);  // deg = in-degree + self-loop
}

// ---------- exclusive scan over cnt -> offs ----------
__global__ __launch_bounds__(SCAN_B) void scan1_k(const int* __restrict__ cnt,
                                                  int* __restrict__ offs,
                                                  int* __restrict__ bsum, int N) {
  __shared__ int sm[SCAN_B];
  int t = threadIdx.x;
  int i = blockIdx.x * SCAN_B + t;
  int v = (i < N) ? cnt[i] : 0;
  int x = v;
  sm[t] = x;
  __syncthreads();
  #pragma unroll
  for (int o = 1; o < SCAN_B; o <<= 1) {
    int y = (t >= o) ? sm[t - o] : 0;
    __syncthreads();
    x += y;
    sm[t] = x;
    __syncthreads();
  }
  if (i < N) offs[i] = x - v;
  if (t == SCAN_B - 1) bsum[blockIdx.x] = x;
}

__global__ __launch_bounds__(512) void scan2_k(int* __restrict__ bsum, int nb) {
  __shared__ int sm[512];
  int t = threadIdx.x;
  int v = (t < nb) ? bsum[t] : 0;
  int x = v;
  sm[t] = x;
  __syncthreads();
  #pragma unroll
  for (int o = 1; o < 512; o <<= 1) {
    int y = (t >= o) ? sm[t - o] : 0;
    __syncthreads();
    x += y;
    sm[t] = x;
    __syncthreads();
  }
  if (t < nb) bsum[t] = x - v;
}

__global__ void scan3_k(int* __restrict__ offs, const int* __restrict__ bsum,
                        int N, int E) {
  int i = blockIdx.x * 256 + threadIdx.x;
  if (i < N) offs[i] = offs[i] + bsum[i / SCAN_B];
  if (i == 0) offs[N] = E;
}

__global__ void bcur_k(const int* __restrict__ offs, int* __restrict__ bcur,
                       int nbkt, int N) {
  int b = blockIdx.x * 256 + threadIdx.x;
  if (b < nbkt) bcur[b] = offs[min(b << BSH, N)];
}

// ---------- binA: scatter packed (src<<8 | dst&255) into dst-bucket order ----
__global__ __launch_bounds__(256) void binA_k(const int* __restrict__ raw,
                                              const int* __restrict__ flag,
                                              int* __restrict__ bcur,
                                              unsigned* __restrict__ pairs, int E) {
  __shared__ int hist[512];
  __shared__ int base[512];
  const int tid = threadIdx.x;
  const int f = flag[0];
  const size_t e0 = (size_t)blockIdx.x * PA_CHUNK;
  for (int i = tid; i < 512; i += 256) hist[i] = 0;
  __syncthreads();
  int es[32], ed[32];
  #pragma unroll
  for (int k = 0; k < 32; ++k) {
    size_t e = e0 + (size_t)k * 256 + tid;
    if (e < (size_t)E) {
      es[k] = f ? raw[2 * e] : raw[e];
      ed[k] = f ? raw[2 * ((size_t)E + e)] : raw[(size_t)E + e];
      atomicAdd(&hist[ed[k] >> BSH], 1);
    } else {
      ed[k] = -1;
    }
  }
  __syncthreads();
  for (int i = tid; i < 512; i += 256) {
    int c = hist[i];
    base[i] = c ? atomicAdd(&bcur[i], c) : 0;
    hist[i] = 0;  // reuse as local cursor
  }
  __syncthreads();
  #pragma unroll
  for (int k = 0; k < 32; ++k) {
    if (ed[k] >= 0) {
      int b = ed[k] >> BSH;
      int pos = base[b] + atomicAdd(&hist[b], 1);
      pairs[pos] = ((unsigned)es[k] << 8) | ((unsigned)ed[k] & 255u);
    }
  }
}

// ---------- binB: per-bucket CSR fill (bucket id is positional) ----------
__global__ __launch_bounds__(256) void binB_k(const unsigned* __restrict__ pairs,
                                              const int* __restrict__ offs,
                                              int* __restrict__ csr, int N) {
  __shared__ int lcnt[256];
  const int tid = threadIdx.x;
  const int n0 = blockIdx.x << BSH;
  const int lo = offs[n0];
  const int hi = offs[min(n0 + 256, N)];
  lcnt[tid] = 0;
  __syncthreads();
  for (int j = lo + tid; j < hi; j += 256) {
    unsigned p = pairs[j];
    int dl = (int)(p & 255u);
    int pos = offs[n0 + dl] + atomicAdd(&lcnt[dl], 1);
    csr[pos] = (int)(p >> 8);
  }
}

// ---------- GEMM1 + fused epilogue: hs = fp16(X @ W1 * dis) ----------
__global__ __launch_bounds__(256) void gemm1_k(const float* __restrict__ A,
                                               const float* __restrict__ B,
                                               const float* __restrict__ dis,
                                               __half* __restrict__ hs, int N) {
  __shared__ float As[64][33];
  __shared__ float Bs[32][128];
  const int tid = threadIdx.x;
  const int tx = tid & 15;
  const int ty = tid >> 4;
  const int m0 = blockIdx.x * 64;
  float acc[4][8];
  #pragma unroll
  for (int i = 0; i < 4; ++i)
    #pragma unroll
    for (int j = 0; j < 8; ++j) acc[i][j] = 0.f;

  for (int k0 = 0; k0 < DIN; k0 += 32) {
    #pragma unroll
    for (int l = 0; l < 2; ++l) {
      int idx = tid + l * 256;
      int r = idx >> 3, c = (idx & 7) * 4;
      int gr = m0 + r;
      float4 v = make_float4(0.f, 0.f, 0.f, 0.f);
      if (gr < N) v = *(const float4*)(A + (size_t)gr * DIN + k0 + c);
      As[r][c + 0] = v.x; As[r][c + 1] = v.y; As[r][c + 2] = v.z; As[r][c + 3] = v.w;
    }
    #pragma unroll
    for (int l = 0; l < 4; ++l) {
      int idx = tid + l * 256;
      int r = idx >> 5, c = (idx & 31) * 4;
      *(float4*)(&Bs[r][c]) = *(const float4*)(B + (size_t)(k0 + r) * DHID + c);
    }
    __syncthreads();
    #pragma unroll
    for (int kk = 0; kk < 32; ++kk) {
      float av[4];
      #pragma unroll
      for (int i = 0; i < 4; ++i) av[i] = As[ty * 4 + i][kk];
      float4 b0 = *(const float4*)(&Bs[kk][tx * 4]);
      float4 b1 = *(const float4*)(&Bs[kk][64 + tx * 4]);
      #pragma unroll
      for (int i = 0; i < 4; ++i) {
        acc[i][0] = fmaf(av[i], b0.x, acc[i][0]);
        acc[i][1] = fmaf(av[i], b0.y, acc[i][1]);
        acc[i][2] = fmaf(av[i], b0.z, acc[i][2]);
        acc[i][3] = fmaf(av[i], b0.w, acc[i][3]);
        acc[i][4] = fmaf(av[i], b1.x, acc[i][4]);
        acc[i][5] = fmaf(av[i], b1.y, acc[i][5]);
        acc[i][6] = fmaf(av[i], b1.z, acc[i][6]);
        acc[i][7] = fmaf(av[i], b1.w, acc[i][7]);
      }
    }
    __syncthreads();
  }
  #pragma unroll
  for (int i = 0; i < 4; ++i) {
    int r = m0 + ty * 4 + i;
    if (r < N) {
      const float dr = dis[r];
      __half t0[4], t1[4];
      #pragma unroll
      for (int j = 0; j < 4; ++j) {
        t0[j] = __float2half_rn(acc[i][j] * dr);
        t1[j] = __float2half_rn(acc[i][4 + j] * dr);
      }
      *(uint2*)(hs + (size_t)r * DHID + tx * 4) = *(uint2*)t0;
      *(uint2*)(hs + (size_t)r * DHID + 64 + tx * 4) = *(uint2*)t1;
    }
  }
}

// ---------- fused agg1: dis_i*(sum hs[s] + hs[i]) + b1 -> relu -> @W2*dis_i ----
// One wave per dst node; lane owns features 2*lane, 2*lane+1.
__global__ __launch_bounds__(256) void agg1_k(const __half* __restrict__ hs,
                                              const float* __restrict__ dis,
                                              const int* __restrict__ offs,
                                              const int* __restrict__ csr,
                                              const float* __restrict__ W2,
                                              const float* __restrict__ b1,
                                              float* __restrict__ gs, int N) {
  const int wid = threadIdx.x >> 6;
  const int lane = threadIdx.x & 63;
  const int i = blockIdx.x * 4 + wid;
  if (i >= N) return;
  const int f = lane * 2;
  float ax = 0.f, ay = 0.f;
  const int beg = offs[i], end = offs[i + 1];
  for (int base = beg; base < end; base += 64) {
    int sj = 0;
    if (base + lane < end) sj = csr[base + lane];  // coalesced edge-id load
    const int n = min(64, end - base);
    for (int t = 0; t < n; ++t) {
      int s = __shfl(sj, t, 64);
      __half2 hv = *(const __half2*)(hs + (size_t)s * DHID + f);
      float2 hf = __half22float2(hv);
      ax += hf.x;
      ay += hf.y;
    }
  }
  // self-loop: + hs[i]  (hs = h*dis, so dis_i*hs_i = h_i*dis_i^2)
  {
    __half2 hv = *(const __half2*)(hs + (size_t)i * DHID + f);
    float2 hf = __half22float2(hv);
    ax += hf.x;
    ay += hf.y;
  }
  const float di = dis[i];
  float v0 = fmaxf(fmaf(ax, di, b1[f]), 0.f);
  float v1 = fmaxf(fmaf(ay, di, b1[f + 1]), 0.f);
  // project to 4 dims, butterfly-reduce across the wave
  float p0 = fmaf(v0, W2[f * 4 + 0], v1 * W2[f * 4 + 4]);
  float p1 = fmaf(v0, W2[f * 4 + 1], v1 * W2[f * 4 + 5]);
  float p2 = fmaf(v0, W2[f * 4 + 2], v1 * W2[f * 4 + 6]);
  float p3 = fmaf(v0, W2[f * 4 + 3], v1 * W2[f * 4 + 7]);
  #pragma unroll
  for (int o = 32; o > 0; o >>= 1) {
    p0 += __shfl_xor(p0, o, 64);
    p1 += __shfl_xor(p1, o, 64);
    p2 += __shfl_xor(p2, o, 64);
    p3 += __shfl_xor(p3, o, 64);
  }
  // store premultiplied gs = g * dis_i for layer 2
  if (lane == 0)
    *(float4*)(gs + (size_t)i * DOUT) = make_float4(p0 * di, p1 * di, p2 * di, p3 * di);
}

// ---------- layer-2: out = dis_i*(sum gs[s] + gs[i]) + b2 ----------
__global__ __launch_bounds__(256) void agg2_k(const float* __restrict__ gs,
                                              const float* __restrict__ dis,
                                              const int* __restrict__ offs,
                                              const int* __restrict__ csr,
                                              const float* __restrict__ b2,
                                              float* __restrict__ out, int N) {
  int i = blockIdx.x * 256 + threadIdx.x;
  if (i >= N) return;
  float a0 = 0.f, a1 = 0.f, a2 = 0.f, a3 = 0.f;
  const int beg = offs[i], end = offs[i + 1];
  for (int j = beg; j < end; ++j) {
    int s = csr[j];
    float4 gv = *(const float4*)(gs + (size_t)s * DOUT);
    a0 += gv.x; a1 += gv.y; a2 += gv.z; a3 += gv.w;
  }
  const float di = dis[i];
  float4 gi = *(const float4*)(gs + (size_t)i * DOUT);
  float4 o4;
  o4.x = fmaf(a0 + gi.x, di, b2[0]);
  o4.y = fmaf(a1 + gi.y, di, b2[1]);
  o4.z = fmaf(a2 + gi.z, di, b2[2]);
  o4.w = fmaf(a3 + gi.w, di, b2[3]);
  *(float4*)(out + (size_t)i * DOUT) = o4;
}

extern "C" void kernel_launch(void* const* d_in, const int* in_sizes, int n_in,
                              void* d_out, int out_size, void* d_ws, size_t ws_size,
                              hipStream_t stream) {
  const float* x  = (const float*)d_in[0];
  const int*   raw = (const int*)d_in[1];
  const float* W1 = (const float*)d_in[2];
  const float* b1 = (const float*)d_in[3];
  const float* W2 = (const float*)d_in[4];
  const float* b2 = (const float*)d_in[5];
  float* out = (float*)d_out;

  const int N = in_sizes[0] / DIN;   // 100000
  const int E = in_sizes[1] / 2;     // 3200000

  char* ws = (char*)d_ws;
  size_t off = 0;
  auto carve = [&](size_t bytes) -> char* {
    char* p = ws + off;
    off = (off + bytes + 255) & ~(size_t)255;
    return p;
  };
  int*      cnt  = (int*)carve((size_t)N * 4);
  float*    dis  = (float*)carve((size_t)N * 4);
  int*      offs = (int*)carve((size_t)(N + 1) * 4);
  int*      csr  = (int*)carve((size_t)E * 4);
  unsigned* pairs= (unsigned*)carve((size_t)E * 4);
  int*      bsum = (int*)carve(512 * 4);
  int*      bcur = (int*)carve(512 * 4);
  int*      flag = (int*)carve(256);
  __half*   hs   = (__half*)carve((size_t)N * DHID * 2);
  float*    gs   = (float*)carve((size_t)N * DOUT * 4);
  (void)ws_size; (void)n_in; (void)out_size;

  const int gE = (E + 255) / 256;
  const int gN = (N + 255) / 256;
  const int nb = (N + SCAN_B - 1) / SCAN_B;       // 391 <= 512
  const int nbkt = (N + (1 << BSH) - 1) >> BSH;   // 391
  const int gA = (E + PA_CHUNK - 1) / PA_CHUNK;   // 391

  detect_i64_k<<<1, 64, 0, stream>>>(raw, flag);
  zero_k<<<gN, 256, 0, stream>>>(cnt, N);
  count_k<<<gE, 256, 0, stream>>>(raw, flag, cnt, E);
  dis_k<<<gN, 256, 0, stream>>>(cnt, dis, N);
  scan1_k<<<nb, SCAN_B, 0, stream>>>(cnt, offs, bsum, N);
  scan2_k<<<1, 512, 0, stream>>>(bsum, nb);
  scan3_k<<<gN, 256, 0, stream>>>(offs, bsum, N, E);
  bcur_k<<<2, 256, 0, stream>>>(offs, bcur, nbkt, N);
  binA_k<<<gA, 256, 0, stream>>>(raw, flag, bcur, pairs, E);
  binB_k<<<nbkt, 256, 0, stream>>>(pairs, offs, csr, N);
  gemm1_k<<<(N + 63) / 64, 256, 0, stream>>>(x, W1, dis, hs, N);
  agg1_k<<<(N + 3) / 4, 256, 0, stream>>>(hs, dis, offs, csr, W2, b1, gs, N);
  agg2_k<<<gN, 256, 0, stream>>>(gs, dis, offs, csr, b2, out, N);
}

// Round 4
// 663.391 us; speedup vs baseline: 1.6770x; 1.2557x over previous
//
#include <hip/hip_runtime.h>
#include <hip/hip_fp16.h>

#define DIN 512
#define DHID 128
#define DOUT 4
#define BSH 8                 // bucket = 256 nodes
#define PA_CHUNK 8192         // edges per binning block (32/thread)
#define AST 72                // padded LDS row stride (fp16) for MFMA slabs

typedef _Float16 f16x8 __attribute__((ext_vector_type(8)));
typedef _Float16 f16x4 __attribute__((ext_vector_type(4)));
typedef float    f32x4 __attribute__((ext_vector_type(4)));

// ---------- edge dtype detection (int64 vs int32 ABI) ----------
__global__ void detect_i64_k(const int* __restrict__ raw, int* __restrict__ flag) {
  if (blockIdx.x == 0 && threadIdx.x == 0) {
    int z = 1;
    for (int k = 0; k < 8; ++k)
      if (raw[2 * k + 1] != 0) z = 0;
    flag[0] = z;
  }
}

// ---------- bucket histogram (391 buckets) via LDS ----------
__global__ __launch_bounds__(256) void bcount_k(const int* __restrict__ raw,
                                                const int* __restrict__ flag,
                                                int* __restrict__ gbcnt, int E) {
  __shared__ int h[512];
  const int tid = threadIdx.x;
  const int f = flag[0];
  for (int i = tid; i < 512; i += 256) h[i] = 0;
  __syncthreads();
  const size_t e0 = (size_t)blockIdx.x * PA_CHUNK;
  #pragma unroll
  for (int k = 0; k < 32; ++k) {
    size_t e = e0 + (size_t)k * 256 + tid;
    if (e < (size_t)E) {
      int d = f ? raw[2 * ((size_t)E + e)] : raw[(size_t)E + e];
      atomicAdd(&h[d >> BSH], 1);
    }
  }
  __syncthreads();
  for (int i = tid; i < 512; i += 256)
    if (h[i]) atomicAdd(&gbcnt[i], h[i]);
}

// ---------- bucket scan (single block) -> boffs, bcur; also offs[N]=E ----------
__global__ __launch_bounds__(512) void bscan_k(const int* __restrict__ gbcnt,
                                               int* __restrict__ boffs,
                                               int* __restrict__ bcur,
                                               int* __restrict__ offs,
                                               int nbkt, int N, int E) {
  __shared__ int sm[512];
  int t = threadIdx.x;
  int v = (t < nbkt) ? gbcnt[t] : 0;
  int x = v;
  sm[t] = x;
  __syncthreads();
  #pragma unroll
  for (int o = 1; o < 512; o <<= 1) {
    int y = (t >= o) ? sm[t - o] : 0;
    __syncthreads();
    x += y;
    sm[t] = x;
    __syncthreads();
  }
  if (t < nbkt) {
    boffs[t] = x - v;
    bcur[t] = x - v;
  }
  if (t == 0) {
    boffs[nbkt] = E;
    offs[N] = E;
  }
}

// ---------- binA: scatter packed (src<<8 | dst&255) into dst-bucket order ----
__global__ __launch_bounds__(256) void binA_k(const int* __restrict__ raw,
                                              const int* __restrict__ flag,
                                              int* __restrict__ bcur,
                                              unsigned* __restrict__ pairs, int E) {
  __shared__ int hist[512];
  __shared__ int base[512];
  const int tid = threadIdx.x;
  const int f = flag[0];
  const size_t e0 = (size_t)blockIdx.x * PA_CHUNK;
  for (int i = tid; i < 512; i += 256) hist[i] = 0;
  __syncthreads();
  int es[32], ed[32];
  #pragma unroll
  for (int k = 0; k < 32; ++k) {
    size_t e = e0 + (size_t)k * 256 + tid;
    if (e < (size_t)E) {
      es[k] = f ? raw[2 * e] : raw[e];
      ed[k] = f ? raw[2 * ((size_t)E + e)] : raw[(size_t)E + e];
      atomicAdd(&hist[ed[k] >> BSH], 1);
    } else {
      ed[k] = -1;
    }
  }
  __syncthreads();
  for (int i = tid; i < 512; i += 256) {
    int c = hist[i];
    base[i] = c ? atomicAdd(&bcur[i], c) : 0;
    hist[i] = 0;  // reuse as local cursor
  }
  __syncthreads();
  #pragma unroll
  for (int k = 0; k < 32; ++k) {
    if (ed[k] >= 0) {
      int b = ed[k] >> BSH;
      int pos = base[b] + atomicAdd(&hist[b], 1);
      pairs[pos] = ((unsigned)es[k] << 8) | ((unsigned)ed[k] & 255u);
    }
  }
}

// ---------- binB: per-bucket local count + scan -> offs/dis, then CSR fill ----
__global__ __launch_bounds__(256) void binB_k(const unsigned* __restrict__ pairs,
                                              const int* __restrict__ boffs,
                                              int* __restrict__ csr,
                                              int* __restrict__ offs,
                                              float* __restrict__ dis, int N) {
  __shared__ int lcnt[256];
  __shared__ int sc[256];
  const int tid = threadIdx.x;
  const int n0 = blockIdx.x << BSH;
  const int lo = boffs[blockIdx.x];
  const int hi = boffs[blockIdx.x + 1];
  lcnt[tid] = 0;
  __syncthreads();
  for (int j = lo + tid; j < hi; j += 256) atomicAdd(&lcnt[(int)(pairs[j] & 255u)], 1);
  __syncthreads();
  int v = lcnt[tid];
  int x = v;
  sc[tid] = x;
  __syncthreads();
  #pragma unroll
  for (int o = 1; o < 256; o <<= 1) {
    int y = (tid >= o) ? sc[tid - o] : 0;
    __syncthreads();
    x += y;
    sc[tid] = x;
    __syncthreads();
  }
  const int base = lo + x - v;   // node's CSR start
  const int node = n0 + tid;
  if (node < N) {
    offs[node] = base;
    dis[node] = rsqrtf((float)v + 1.0f);   // deg = in-degree + self-loop
  }
  __syncthreads();
  lcnt[tid] = base;   // reuse as cursor
  __syncthreads();
  for (int j = lo + tid; j < hi; j += 256) {
    unsigned p = pairs[j];
    int dl = (int)(p & 255u);
    int pos = atomicAdd(&lcnt[dl], 1);
    csr[pos] = (int)(p >> 8);   // lands in this bucket's span -> L2 absorbs
  }
}

// ---------- W1 split to fp16 hi/lo, transposed [128][512] ----------
__global__ __launch_bounds__(256) void wsplit_k(const float* __restrict__ W1,
                                                __half* __restrict__ Wth,
                                                __half* __restrict__ Wtl) {
  int idx = blockIdx.x * 256 + threadIdx.x;   // 0..65535
  if (idx >= DIN * DHID) return;
  int k = idx >> 7;    // 0..511
  int n = idx & 127;
  float w = W1[idx];   // W1[k][n], coalesced read
  _Float16 hi = (_Float16)w;
  _Float16 lo = (_Float16)(w - (float)hi);
  Wth[(size_t)n * DIN + k] = *(__half*)&hi;
  Wtl[(size_t)n * DIN + k] = *(__half*)&lo;
}

// ---------- GEMM1 via split-fp16 MFMA: hs = fp16((X@W1) * dis) ----------
// 128x128 tile, K staged in BK=64 slabs. x = xh + xl (fp16 pair); h =
// xh*Wh + xh*Wl + xl*Wh (lo*lo dropped, ~2^-22) -> fp32-equivalent accuracy.
// Fragment layouts (verified m89/m120): A/B [m|n=lane&15][k=quad*8+j],
// C/D col=lane&15, row=quad*4+reg.
__global__ __launch_bounds__(256, 2) void gemm1_k(const float* __restrict__ A,
                                                  const __half* __restrict__ Bth,
                                                  const __half* __restrict__ Btl,
                                                  const float* __restrict__ dis,
                                                  __half* __restrict__ hs, int N) {
  __shared__ _Float16 smem[4 * 128 * AST];   // Ah | Al | Bh | Bl = 73728 B
  __shared__ float sdis[128];
  _Float16* sAh = smem;
  _Float16* sAl = smem + 128 * AST;
  _Float16* sBh = smem + 2 * 128 * AST;
  _Float16* sBl = smem + 3 * 128 * AST;
  const int tid = threadIdx.x;
  const int wave = tid >> 6, lane = tid & 63;
  const int lr = lane & 15, quad = lane >> 4;
  const int m0 = blockIdx.x * 128;
  const int mbase = (wave >> 1) * 64;   // wave owns 64x64 of the 128x128 tile
  const int nbase = (wave & 1) * 64;
  if (tid < 128) sdis[tid] = (m0 + tid < N) ? dis[m0 + tid] : 0.f;

  f32x4 acc[4][4];
  #pragma unroll
  for (int mt = 0; mt < 4; ++mt)
    #pragma unroll
    for (int nt = 0; nt < 4; ++nt) acc[mt][nt] = (f32x4){0.f, 0.f, 0.f, 0.f};

  for (int k0 = 0; k0 < DIN; k0 += 64) {
    // stage A slab 128x64 fp32 -> fp16 hi/lo (8 float4 per thread)
    #pragma unroll
    for (int l = 0; l < 8; ++l) {
      int idx = l * 256 + tid;
      int row = idx >> 4;
      int kk = (idx & 15) << 2;
      int gr = m0 + row;
      float4 v = make_float4(0.f, 0.f, 0.f, 0.f);
      if (gr < N) v = *(const float4*)(A + (size_t)gr * DIN + k0 + kk);
      _Float16 h0 = (_Float16)v.x, h1 = (_Float16)v.y,
               h2 = (_Float16)v.z, h3 = (_Float16)v.w;
      f16x4 hi4 = {h0, h1, h2, h3};
      f16x4 lo4 = {(_Float16)(v.x - (float)h0), (_Float16)(v.y - (float)h1),
                   (_Float16)(v.z - (float)h2), (_Float16)(v.w - (float)h3)};
      *(f16x4*)&sAh[row * AST + kk] = hi4;
      *(f16x4*)&sAl[row * AST + kk] = lo4;
    }
    // stage B slab 128x64 fp16 hi/lo (4 x 16B per thread each)
    #pragma unroll
    for (int l = 0; l < 4; ++l) {
      int idx = l * 256 + tid;
      int row = idx >> 3;
      int kk = (idx & 7) << 3;
      *(f16x8*)&sBh[row * AST + kk] =
          *(const f16x8*)(Bth + (size_t)row * DIN + k0 + kk);
      *(f16x8*)&sBl[row * AST + kk] =
          *(const f16x8*)(Btl + (size_t)row * DIN + k0 + kk);
    }
    __syncthreads();
    #pragma unroll
    for (int ks = 0; ks < 2; ++ks) {
      const int ko = ks * 32 + quad * 8;
      f16x8 ah[4], al[4];
      #pragma unroll
      for (int mt = 0; mt < 4; ++mt) {
        int r = mbase + mt * 16 + lr;
        ah[mt] = *(const f16x8*)&sAh[r * AST + ko];
        al[mt] = *(const f16x8*)&sAl[r * AST + ko];
      }
      #pragma unroll
      for (int nt = 0; nt < 4; ++nt) {
        int c = nbase + nt * 16 + lr;
        f16x8 bh = *(const f16x8*)&sBh[c * AST + ko];
        f16x8 bl = *(const f16x8*)&sBl[c * AST + ko];
        #pragma unroll
        for (int mt = 0; mt < 4; ++mt) {
          acc[mt][nt] = __builtin_amdgcn_mfma_f32_16x16x32_f16(al[mt], bh, acc[mt][nt], 0, 0, 0);
          acc[mt][nt] = __builtin_amdgcn_mfma_f32_16x16x32_f16(ah[mt], bl, acc[mt][nt], 0, 0, 0);
          acc[mt][nt] = __builtin_amdgcn_mfma_f32_16x16x32_f16(ah[mt], bh, acc[mt][nt], 0, 0, 0);
        }
      }
    }
    __syncthreads();
  }
  // epilogue: scale by dis, round to fp16 in LDS [128][136], coalesced store
  #pragma unroll
  for (int mt = 0; mt < 4; ++mt) {
    #pragma unroll
    for (int nt = 0; nt < 4; ++nt) {
      int col = nbase + nt * 16 + lr;
      #pragma unroll
      for (int r = 0; r < 4; ++r) {
        int row = mbase + mt * 16 + quad * 4 + r;
        smem[row * 136 + col] = (_Float16)(acc[mt][nt][r] * sdis[row]);
      }
    }
  }
  __syncthreads();
  #pragma unroll
  for (int l = 0; l < 8; ++l) {
    int idx = l * 256 + tid;
    int row = idx >> 4;
    int c = (idx & 15) << 3;
    int gr = m0 + row;
    if (gr < N)
      *(uint4*)(hs + (size_t)gr * DHID + c) = *(uint4*)&smem[row * 136 + c];
  }
}

// ---------- fused agg1: dis_i*(sum hs[s] + hs[i]) + b1 -> relu -> @W2*dis_i ----
__global__ __launch_bounds__(256) void agg1_k(const __half* __restrict__ hs,
                                              const float* __restrict__ dis,
                                              const int* __restrict__ offs,
                                              const int* __restrict__ csr,
                                              const float* __restrict__ W2,
                                              const float* __restrict__ b1,
                                              float* __restrict__ gs, int N) {
  const int wid = threadIdx.x >> 6;
  const int lane = threadIdx.x & 63;
  const int i = blockIdx.x * 4 + wid;
  if (i >= N) return;
  const int f = lane * 2;
  float ax = 0.f, ay = 0.f;
  const int beg = offs[i], end = offs[i + 1];
  for (int base = beg; base < end; base += 64) {
    int sj = 0;
    if (base + lane < end) sj = csr[base + lane];  // coalesced edge-id load
    const int n = min(64, end - base);
    for (int t = 0; t < n; ++t) {
      int s = __shfl(sj, t, 64);
      __half2 hv = *(const __half2*)(hs + (size_t)s * DHID + f);
      float2 hf = __half22float2(hv);
      ax += hf.x;
      ay += hf.y;
    }
  }
  {  // self-loop
    __half2 hv = *(const __half2*)(hs + (size_t)i * DHID + f);
    float2 hf = __half22float2(hv);
    ax += hf.x;
    ay += hf.y;
  }
  const float di = dis[i];
  float v0 = fmaxf(fmaf(ax, di, b1[f]), 0.f);
  float v1 = fmaxf(fmaf(ay, di, b1[f + 1]), 0.f);
  float p0 = fmaf(v0, W2[f * 4 + 0], v1 * W2[f * 4 + 4]);
  float p1 = fmaf(v0, W2[f * 4 + 1], v1 * W2[f * 4 + 5]);
  float p2 = fmaf(v0, W2[f * 4 + 2], v1 * W2[f * 4 + 6]);
  float p3 = fmaf(v0, W2[f * 4 + 3], v1 * W2[f * 4 + 7]);
  #pragma unroll
  for (int o = 32; o > 0; o >>= 1) {
    p0 += __shfl_xor(p0, o, 64);
    p1 += __shfl_xor(p1, o, 64);
    p2 += __shfl_xor(p2, o, 64);
    p3 += __shfl_xor(p3, o, 64);
  }
  if (lane == 0)
    *(float4*)(gs + (size_t)i * DOUT) = make_float4(p0 * di, p1 * di, p2 * di, p3 * di);
}

// ---------- layer-2: out = dis_i*(sum gs[s] + gs[i]) + b2 ----------
__global__ __launch_bounds__(256) void agg2_k(const float* __restrict__ gs,
                                              const float* __restrict__ dis,
                                              const int* __restrict__ offs,
                                              const int* __restrict__ csr,
                                              const float* __restrict__ b2,
                                              float* __restrict__ out, int N) {
  int i = blockIdx.x * 256 + threadIdx.x;
  if (i >= N) return;
  float a0 = 0.f, a1 = 0.f, a2 = 0.f, a3 = 0.f;
  const int beg = offs[i], end = offs[i + 1];
  for (int j = beg; j < end; ++j) {
    int s = csr[j];
    float4 gv = *(const float4*)(gs + (size_t)s * DOUT);
    a0 += gv.x; a1 += gv.y; a2 += gv.z; a3 += gv.w;
  }
  const float di = dis[i];
  float4 gi = *(const float4*)(gs + (size_t)i * DOUT);
  float4 o4;
  o4.x = fmaf(a0 + gi.x, di, b2[0]);
  o4.y = fmaf(a1 + gi.y, di, b2[1]);
  o4.z = fmaf(a2 + gi.z, di, b2[2]);
  o4.w = fmaf(a3 + gi.w, di, b2[3]);
  *(float4*)(out + (size_t)i * DOUT) = o4;
}

extern "C" void kernel_launch(void* const* d_in, const int* in_sizes, int n_in,
                              void* d_out, int out_size, void* d_ws, size_t ws_size,
                              hipStream_t stream) {
  const float* x  = (const float*)d_in[0];
  const int*   raw = (const int*)d_in[1];
  const float* W1 = (const float*)d_in[2];
  const float* b1 = (const float*)d_in[3];
  const float* W2 = (const float*)d_in[4];
  const float* b2 = (const float*)d_in[5];
  float* out = (float*)d_out;

  const int N = in_sizes[0] / DIN;   // 100000
  const int E = in_sizes[1] / 2;     // 3200000

  char* ws = (char*)d_ws;
  size_t off = 0;
  auto carve = [&](size_t bytes) -> char* {
    char* p = ws + off;
    off = (off + bytes + 255) & ~(size_t)255;
    return p;
  };
  float*    dis  = (float*)carve((size_t)N * 4);
  int*      offs = (int*)carve((size_t)(N + 1) * 4);
  int*      csr  = (int*)carve((size_t)E * 4);
  unsigned* pairs= (unsigned*)carve((size_t)E * 4);
  int*      boffs= (int*)carve(513 * 4);
  int*      bcur = (int*)carve(512 * 4);
  int*      gbcnt= (int*)carve(512 * 4);
  int*      flag = (int*)carve(256);
  __half*   Wth  = (__half*)carve((size_t)DIN * DHID * 2);
  __half*   Wtl  = (__half*)carve((size_t)DIN * DHID * 2);
  __half*   hs   = (__half*)carve((size_t)N * DHID * 2);
  float*    gs   = (float*)carve((size_t)N * DOUT * 4);
  (void)ws_size; (void)n_in; (void)out_size;

  const int gN = (N + 255) / 256;
  const int nbkt = (N + (1 << BSH) - 1) >> BSH;   // 391
  const int gA = (E + PA_CHUNK - 1) / PA_CHUNK;   // 391

  detect_i64_k<<<1, 64, 0, stream>>>(raw, flag);
  hipMemsetAsync(gbcnt, 0, 512 * 4, stream);
  bcount_k<<<gA, 256, 0, stream>>>(raw, flag, gbcnt, E);
  bscan_k<<<1, 512, 0, stream>>>(gbcnt, boffs, bcur, offs, nbkt, N, E);
  binA_k<<<gA, 256, 0, stream>>>(raw, flag, bcur, pairs, E);
  binB_k<<<nbkt, 256, 0, stream>>>(pairs, boffs, csr, offs, dis, N);
  wsplit_k<<<(DIN * DHID + 255) / 256, 256, 0, stream>>>(W1, Wth, Wtl);
  gemm1_k<<<(N + 127) / 128, 256, 0, stream>>>(x, Wth, Wtl, dis, hs, N);
  agg1_k<<<(N + 3) / 4, 256, 0, stream>>>(hs, dis, offs, csr, W2, b1, gs, N);
  agg2_k<<<gN, 256, 0, stream>>>(gs, dis, offs, csr, b2, out, N);
}

// Round 5
// 571.922 us; speedup vs baseline: 1.9452x; 1.1599x over previous
//
#include <hip/hip_runtime.h>
#include <hip/hip_fp16.h>

#define DIN 512
#define DHID 128
#define DOUT 4
#define BSH 8                 // bucket = 256 nodes
#define PA_CHUNK 8192         // edges per binning block (32/thread)
#define AST 72                // padded LDS row stride (fp16) for MFMA slabs

typedef _Float16 f16x8 __attribute__((ext_vector_type(8)));
typedef _Float16 f16x4 __attribute__((ext_vector_type(4)));
typedef float    f32x4 __attribute__((ext_vector_type(4)));

// ---------- edge dtype detection (int64 vs int32 ABI) ----------
__global__ void detect_i64_k(const int* __restrict__ raw, int* __restrict__ flag) {
  if (blockIdx.x == 0 && threadIdx.x == 0) {
    int z = 1;
    for (int k = 0; k < 8; ++k)
      if (raw[2 * k + 1] != 0) z = 0;
    flag[0] = z;
  }
}

// ---------- bucket histogram (391 buckets) via LDS ----------
__global__ __launch_bounds__(256) void bcount_k(const int* __restrict__ raw,
                                                const int* __restrict__ flag,
                                                int* __restrict__ gbcnt, int E) {
  __shared__ int h[512];
  const int tid = threadIdx.x;
  const int f = flag[0];
  for (int i = tid; i < 512; i += 256) h[i] = 0;
  __syncthreads();
  const size_t e0 = (size_t)blockIdx.x * PA_CHUNK;
  #pragma unroll
  for (int k = 0; k < 32; ++k) {
    size_t e = e0 + (size_t)k * 256 + tid;
    if (e < (size_t)E) {
      int d = f ? raw[2 * ((size_t)E + e)] : raw[(size_t)E + e];
      atomicAdd(&h[d >> BSH], 1);
    }
  }
  __syncthreads();
  for (int i = tid; i < 512; i += 256)
    if (h[i]) atomicAdd(&gbcnt[i], h[i]);
}

// ---------- bucket scan (single block) -> boffs, bcur; also offs[N]=E ----------
__global__ __launch_bounds__(512) void bscan_k(const int* __restrict__ gbcnt,
                                               int* __restrict__ boffs,
                                               int* __restrict__ bcur,
                                               int* __restrict__ offs,
                                               int nbkt, int N, int E) {
  __shared__ int sm[512];
  int t = threadIdx.x;
  int v = (t < nbkt) ? gbcnt[t] : 0;
  int x = v;
  sm[t] = x;
  __syncthreads();
  #pragma unroll
  for (int o = 1; o < 512; o <<= 1) {
    int y = (t >= o) ? sm[t - o] : 0;
    __syncthreads();
    x += y;
    sm[t] = x;
    __syncthreads();
  }
  if (t < nbkt) {
    boffs[t] = x - v;
    bcur[t] = x - v;
  }
  if (t == 0) {
    boffs[nbkt] = E;
    offs[N] = E;
  }
}

// ---------- binA: scatter packed (src<<8 | dst&255) into dst-bucket order ----
__global__ __launch_bounds__(256) void binA_k(const int* __restrict__ raw,
                                              const int* __restrict__ flag,
                                              int* __restrict__ bcur,
                                              unsigned* __restrict__ pairs, int E) {
  __shared__ int hist[512];
  __shared__ int base[512];
  const int tid = threadIdx.x;
  const int f = flag[0];
  const size_t e0 = (size_t)blockIdx.x * PA_CHUNK;
  for (int i = tid; i < 512; i += 256) hist[i] = 0;
  __syncthreads();
  int es[32], ed[32];
  #pragma unroll
  for (int k = 0; k < 32; ++k) {
    size_t e = e0 + (size_t)k * 256 + tid;
    if (e < (size_t)E) {
      es[k] = f ? raw[2 * e] : raw[e];
      ed[k] = f ? raw[2 * ((size_t)E + e)] : raw[(size_t)E + e];
      atomicAdd(&hist[ed[k] >> BSH], 1);
    } else {
      ed[k] = -1;
    }
  }
  __syncthreads();
  for (int i = tid; i < 512; i += 256) {
    int c = hist[i];
    base[i] = c ? atomicAdd(&bcur[i], c) : 0;
    hist[i] = 0;  // reuse as local cursor
  }
  __syncthreads();
  #pragma unroll
  for (int k = 0; k < 32; ++k) {
    if (ed[k] >= 0) {
      int b = ed[k] >> BSH;
      int pos = base[b] + atomicAdd(&hist[b], 1);
      pairs[pos] = ((unsigned)es[k] << 8) | ((unsigned)ed[k] & 255u);
    }
  }
}

// ---------- binB: per-bucket local count + scan -> offs/dis, then CSR fill ----
__global__ __launch_bounds__(256) void binB_k(const unsigned* __restrict__ pairs,
                                              const int* __restrict__ boffs,
                                              int* __restrict__ csr,
                                              int* __restrict__ offs,
                                              float* __restrict__ dis, int N) {
  __shared__ int lcnt[256];
  __shared__ int sc[256];
  const int tid = threadIdx.x;
  const int n0 = blockIdx.x << BSH;
  const int lo = boffs[blockIdx.x];
  const int hi = boffs[blockIdx.x + 1];
  lcnt[tid] = 0;
  __syncthreads();
  for (int j = lo + tid; j < hi; j += 256) atomicAdd(&lcnt[(int)(pairs[j] & 255u)], 1);
  __syncthreads();
  int v = lcnt[tid];
  int x = v;
  sc[tid] = x;
  __syncthreads();
  #pragma unroll
  for (int o = 1; o < 256; o <<= 1) {
    int y = (tid >= o) ? sc[tid - o] : 0;
    __syncthreads();
    x += y;
    sc[tid] = x;
    __syncthreads();
  }
  const int base = lo + x - v;   // node's CSR start
  const int node = n0 + tid;
  if (node < N) {
    offs[node] = base;
    dis[node] = rsqrtf((float)v + 1.0f);   // deg = in-degree + self-loop
  }
  __syncthreads();
  lcnt[tid] = base;   // reuse as cursor
  __syncthreads();
  for (int j = lo + tid; j < hi; j += 256) {
    unsigned p = pairs[j];
    int dl = (int)(p & 255u);
    int pos = atomicAdd(&lcnt[dl], 1);
    csr[pos] = (int)(p >> 8);   // lands in this bucket's span -> L2 absorbs
  }
}

// ---------- W1 split to fp16 hi/lo, transposed [128][512] ----------
__global__ __launch_bounds__(256) void wsplit_k(const float* __restrict__ W1,
                                                __half* __restrict__ Wth,
                                                __half* __restrict__ Wtl) {
  int idx = blockIdx.x * 256 + threadIdx.x;   // 0..65535
  if (idx >= DIN * DHID) return;
  int k = idx >> 7;    // 0..511
  int n = idx & 127;
  float w = W1[idx];   // W1[k][n], coalesced read
  _Float16 hi = (_Float16)w;
  _Float16 lo = (_Float16)(w - (float)hi);
  Wth[(size_t)n * DIN + k] = *(__half*)&hi;
  Wtl[(size_t)n * DIN + k] = *(__half*)&lo;
}

// ---------- GEMM1 via split-fp16 MFMA: hs = fp16((X@W1) * dis) ----------
__global__ __launch_bounds__(256, 2) void gemm1_k(const float* __restrict__ A,
                                                  const __half* __restrict__ Bth,
                                                  const __half* __restrict__ Btl,
                                                  const float* __restrict__ dis,
                                                  __half* __restrict__ hs, int N) {
  __shared__ _Float16 smem[4 * 128 * AST];   // Ah | Al | Bh | Bl = 73728 B
  __shared__ float sdis[128];
  _Float16* sAh = smem;
  _Float16* sAl = smem + 128 * AST;
  _Float16* sBh = smem + 2 * 128 * AST;
  _Float16* sBl = smem + 3 * 128 * AST;
  const int tid = threadIdx.x;
  const int wave = tid >> 6, lane = tid & 63;
  const int lr = lane & 15, quad = lane >> 4;
  const int m0 = blockIdx.x * 128;
  const int mbase = (wave >> 1) * 64;   // wave owns 64x64 of the 128x128 tile
  const int nbase = (wave & 1) * 64;
  if (tid < 128) sdis[tid] = (m0 + tid < N) ? dis[m0 + tid] : 0.f;

  f32x4 acc[4][4];
  #pragma unroll
  for (int mt = 0; mt < 4; ++mt)
    #pragma unroll
    for (int nt = 0; nt < 4; ++nt) acc[mt][nt] = (f32x4){0.f, 0.f, 0.f, 0.f};

  for (int k0 = 0; k0 < DIN; k0 += 64) {
    #pragma unroll
    for (int l = 0; l < 8; ++l) {
      int idx = l * 256 + tid;
      int row = idx >> 4;
      int kk = (idx & 15) << 2;
      int gr = m0 + row;
      float4 v = make_float4(0.f, 0.f, 0.f, 0.f);
      if (gr < N) v = *(const float4*)(A + (size_t)gr * DIN + k0 + kk);
      _Float16 h0 = (_Float16)v.x, h1 = (_Float16)v.y,
               h2 = (_Float16)v.z, h3 = (_Float16)v.w;
      f16x4 hi4 = {h0, h1, h2, h3};
      f16x4 lo4 = {(_Float16)(v.x - (float)h0), (_Float16)(v.y - (float)h1),
                   (_Float16)(v.z - (float)h2), (_Float16)(v.w - (float)h3)};
      *(f16x4*)&sAh[row * AST + kk] = hi4;
      *(f16x4*)&sAl[row * AST + kk] = lo4;
    }
    #pragma unroll
    for (int l = 0; l < 4; ++l) {
      int idx = l * 256 + tid;
      int row = idx >> 3;
      int kk = (idx & 7) << 3;
      *(f16x8*)&sBh[row * AST + kk] =
          *(const f16x8*)(Bth + (size_t)row * DIN + k0 + kk);
      *(f16x8*)&sBl[row * AST + kk] =
          *(const f16x8*)(Btl + (size_t)row * DIN + k0 + kk);
    }
    __syncthreads();
    #pragma unroll
    for (int ks = 0; ks < 2; ++ks) {
      const int ko = ks * 32 + quad * 8;
      f16x8 ah[4], al[4];
      #pragma unroll
      for (int mt = 0; mt < 4; ++mt) {
        int r = mbase + mt * 16 + lr;
        ah[mt] = *(const f16x8*)&sAh[r * AST + ko];
        al[mt] = *(const f16x8*)&sAl[r * AST + ko];
      }
      #pragma unroll
      for (int nt = 0; nt < 4; ++nt) {
        int c = nbase + nt * 16 + lr;
        f16x8 bh = *(const f16x8*)&sBh[c * AST + ko];
        f16x8 bl = *(const f16x8*)&sBl[c * AST + ko];
        #pragma unroll
        for (int mt = 0; mt < 4; ++mt) {
          acc[mt][nt] = __builtin_amdgcn_mfma_f32_16x16x32_f16(al[mt], bh, acc[mt][nt], 0, 0, 0);
          acc[mt][nt] = __builtin_amdgcn_mfma_f32_16x16x32_f16(ah[mt], bl, acc[mt][nt], 0, 0, 0);
          acc[mt][nt] = __builtin_amdgcn_mfma_f32_16x16x32_f16(ah[mt], bh, acc[mt][nt], 0, 0, 0);
        }
      }
    }
    __syncthreads();
  }
  // epilogue: scale by dis, round to fp16 in LDS [128][136], coalesced store
  #pragma unroll
  for (int mt = 0; mt < 4; ++mt) {
    #pragma unroll
    for (int nt = 0; nt < 4; ++nt) {
      int col = nbase + nt * 16 + lr;
      #pragma unroll
      for (int r = 0; r < 4; ++r) {
        int row = mbase + mt * 16 + quad * 4 + r;
        smem[row * 136 + col] = (_Float16)(acc[mt][nt][r] * sdis[row]);
      }
    }
  }
  __syncthreads();
  #pragma unroll
  for (int l = 0; l < 8; ++l) {
    int idx = l * 256 + tid;
    int row = idx >> 4;
    int c = (idx & 15) << 3;
    int gr = m0 + row;
    if (gr < N)
      *(uint4*)(hs + (size_t)gr * DHID + c) = *(uint4*)&smem[row * 136 + c];
  }
}

// ---------- fused agg1, unroll-8 gather for memory-level parallelism ----------
__global__ __launch_bounds__(256) void agg1_k(const __half* __restrict__ hs,
                                              const float* __restrict__ dis,
                                              const int* __restrict__ offs,
                                              const int* __restrict__ csr,
                                              const float* __restrict__ W2,
                                              const float* __restrict__ b1,
                                              float* __restrict__ gs, int N) {
  const int wid = threadIdx.x >> 6;
  const int lane = threadIdx.x & 63;
  const int i = blockIdx.x * 4 + wid;
  if (i >= N) return;
  const int f = lane * 2;
  const __half* hp = hs + f;   // lane-fixed column base
  float ax = 0.f, ay = 0.f;
  const int beg = offs[i], end = offs[i + 1];
  for (int base = beg; base < end; base += 64) {
    int sj = 0;
    if (base + lane < end) sj = csr[base + lane];  // coalesced edge-id load
    const int n = min(64, end - base);
    int t = 0;
    for (; t + 8 <= n; t += 8) {   // 8 independent gathers in flight
      int s0 = __shfl(sj, t + 0, 64), s1 = __shfl(sj, t + 1, 64);
      int s2 = __shfl(sj, t + 2, 64), s3 = __shfl(sj, t + 3, 64);
      int s4 = __shfl(sj, t + 4, 64), s5 = __shfl(sj, t + 5, 64);
      int s6 = __shfl(sj, t + 6, 64), s7 = __shfl(sj, t + 7, 64);
      __half2 h0 = *(const __half2*)(hp + (size_t)s0 * DHID);
      __half2 h1 = *(const __half2*)(hp + (size_t)s1 * DHID);
      __half2 h2 = *(const __half2*)(hp + (size_t)s2 * DHID);
      __half2 h3 = *(const __half2*)(hp + (size_t)s3 * DHID);
      __half2 h4 = *(const __half2*)(hp + (size_t)s4 * DHID);
      __half2 h5 = *(const __half2*)(hp + (size_t)s5 * DHID);
      __half2 h6 = *(const __half2*)(hp + (size_t)s6 * DHID);
      __half2 h7 = *(const __half2*)(hp + (size_t)s7 * DHID);
      float2 f0 = __half22float2(h0), f1 = __half22float2(h1);
      float2 f2 = __half22float2(h2), f3 = __half22float2(h3);
      float2 f4 = __half22float2(h4), f5 = __half22float2(h5);
      float2 f6 = __half22float2(h6), f7 = __half22float2(h7);
      ax += ((f0.x + f1.x) + (f2.x + f3.x)) + ((f4.x + f5.x) + (f6.x + f7.x));
      ay += ((f0.y + f1.y) + (f2.y + f3.y)) + ((f4.y + f5.y) + (f6.y + f7.y));
    }
    for (; t < n; ++t) {
      int s = __shfl(sj, t, 64);
      float2 hf = __half22float2(*(const __half2*)(hp + (size_t)s * DHID));
      ax += hf.x;
      ay += hf.y;
    }
  }
  {  // self-loop
    float2 hf = __half22float2(*(const __half2*)(hp + (size_t)i * DHID));
    ax += hf.x;
    ay += hf.y;
  }
  const float di = dis[i];
  float v0 = fmaxf(fmaf(ax, di, b1[f]), 0.f);
  float v1 = fmaxf(fmaf(ay, di, b1[f + 1]), 0.f);
  float p0 = fmaf(v0, W2[f * 4 + 0], v1 * W2[f * 4 + 4]);
  float p1 = fmaf(v0, W2[f * 4 + 1], v1 * W2[f * 4 + 5]);
  float p2 = fmaf(v0, W2[f * 4 + 2], v1 * W2[f * 4 + 6]);
  float p3 = fmaf(v0, W2[f * 4 + 3], v1 * W2[f * 4 + 7]);
  #pragma unroll
  for (int o = 32; o > 0; o >>= 1) {
    p0 += __shfl_xor(p0, o, 64);
    p1 += __shfl_xor(p1, o, 64);
    p2 += __shfl_xor(p2, o, 64);
    p3 += __shfl_xor(p3, o, 64);
  }
  if (lane == 0)
    *(float4*)(gs + (size_t)i * DOUT) = make_float4(p0 * di, p1 * di, p2 * di, p3 * di);
}

// ---------- layer-2: out = dis_i*(sum gs[s] + gs[i]) + b2, unroll-4 ----------
__global__ __launch_bounds__(256) void agg2_k(const float* __restrict__ gs,
                                              const float* __restrict__ dis,
                                              const int* __restrict__ offs,
                                              const int* __restrict__ csr,
                                              const float* __restrict__ b2,
                                              float* __restrict__ out, int N) {
  int i = blockIdx.x * 256 + threadIdx.x;
  if (i >= N) return;
  float a0 = 0.f, a1 = 0.f, a2 = 0.f, a3 = 0.f;
  const int beg = offs[i], end = offs[i + 1];
  int j = beg;
  for (; j + 4 <= end; j += 4) {
    int s0 = csr[j], s1 = csr[j + 1], s2 = csr[j + 2], s3 = csr[j + 3];
    float4 g0 = *(const float4*)(gs + (size_t)s0 * DOUT);
    float4 g1 = *(const float4*)(gs + (size_t)s1 * DOUT);
    float4 g2 = *(const float4*)(gs + (size_t)s2 * DOUT);
    float4 g3 = *(const float4*)(gs + (size_t)s3 * DOUT);
    a0 += (g0.x + g1.x) + (g2.x + g3.x);
    a1 += (g0.y + g1.y) + (g2.y + g3.y);
    a2 += (g0.z + g1.z) + (g2.z + g3.z);
    a3 += (g0.w + g1.w) + (g2.w + g3.w);
  }
  for (; j < end; ++j) {
    int s = csr[j];
    float4 gv = *(const float4*)(gs + (size_t)s * DOUT);
    a0 += gv.x; a1 += gv.y; a2 += gv.z; a3 += gv.w;
  }
  const float di = dis[i];
  float4 gi = *(const float4*)(gs + (size_t)i * DOUT);
  float4 o4;
  o4.x = fmaf(a0 + gi.x, di, b2[0]);
  o4.y = fmaf(a1 + gi.y, di, b2[1]);
  o4.z = fmaf(a2 + gi.z, di, b2[2]);
  o4.w = fmaf(a3 + gi.w, di, b2[3]);
  *(float4*)(out + (size_t)i * DOUT) = o4;
}

extern "C" void kernel_launch(void* const* d_in, const int* in_sizes, int n_in,
                              void* d_out, int out_size, void* d_ws, size_t ws_size,
                              hipStream_t stream) {
  const float* x  = (const float*)d_in[0];
  const int*   raw = (const int*)d_in[1];
  const float* W1 = (const float*)d_in[2];
  const float* b1 = (const float*)d_in[3];
  const float* W2 = (const float*)d_in[4];
  const float* b2 = (const float*)d_in[5];
  float* out = (float*)d_out;

  const int N = in_sizes[0] / DIN;   // 100000
  const int E = in_sizes[1] / 2;     // 3200000

  char* ws = (char*)d_ws;
  size_t off = 0;
  auto carve = [&](size_t bytes) -> char* {
    char* p = ws + off;
    off = (off + bytes + 255) & ~(size_t)255;
    return p;
  };
  float*    dis  = (float*)carve((size_t)N * 4);
  int*      offs = (int*)carve((size_t)(N + 1) * 4);
  int*      csr  = (int*)carve((size_t)E * 4);
  unsigned* pairs= (unsigned*)carve((size_t)E * 4);
  int*      boffs= (int*)carve(513 * 4);
  int*      bcur = (int*)carve(512 * 4);
  int*      gbcnt= (int*)carve(512 * 4);
  int*      flag = (int*)carve(256);
  __half*   Wth  = (__half*)carve((size_t)DIN * DHID * 2);
  __half*   Wtl  = (__half*)carve((size_t)DIN * DHID * 2);
  __half*   hs   = (__half*)carve((size_t)N * DHID * 2);
  float*    gs   = (float*)carve((size_t)N * DOUT * 4);
  (void)ws_size; (void)n_in; (void)out_size;

  const int gN = (N + 255) / 256;
  const int nbkt = (N + (1 << BSH) - 1) >> BSH;   // 391
  const int gA = (E + PA_CHUNK - 1) / PA_CHUNK;   // 391

  detect_i64_k<<<1, 64, 0, stream>>>(raw, flag);
  hipMemsetAsync(gbcnt, 0, 512 * 4, stream);
  bcount_k<<<gA, 256, 0, stream>>>(raw, flag, gbcnt, E);
  bscan_k<<<1, 512, 0, stream>>>(gbcnt, boffs, bcur, offs, nbkt, N, E);
  binA_k<<<gA, 256, 0, stream>>>(raw, flag, bcur, pairs, E);
  binB_k<<<nbkt, 256, 0, stream>>>(pairs, boffs, csr, offs, dis, N);
  wsplit_k<<<(DIN * DHID + 255) / 256, 256, 0, stream>>>(W1, Wth, Wtl);
  gemm1_k<<<(N + 127) / 128, 256, 0, stream>>>(x, Wth, Wtl, dis, hs, N);
  agg1_k<<<(N + 3) / 4, 256, 0, stream>>>(hs, dis, offs, csr, W2, b1, gs, N);
  agg2_k<<<gN, 256, 0, stream>>>(gs, dis, offs, csr, b2, out, N);
}